// Round 9
// baseline (380.355 us; speedup 1.0000x reference)
//
#include <hip/hip_runtime.h>
#include <hip/hip_bf16.h>

#define B_ 128
#define T_ 300
#define TC_ 20
#define DW_ 16
#define DC_ 32
#define UC_ 32
#define UM_ 64
#define POS_ 20
#define PAR_ 8
#define VW_ 1834
#define VC_ 132
#define DIN_ 76
#define XS_ 80
#define NROW (B_*T_)

typedef _Float16 half_t;
typedef half_t h2 __attribute__((ext_vector_type(2)));

__device__ __forceinline__ float fast_sig(float x){
  return __builtin_amdgcn_rcpf(1.f + __expf(-x));
}
__device__ __forceinline__ float fast_tanh(float x){
  return __builtin_amdgcn_rcpf(1.f + __expf(-2.f*x))*2.f - 1.f;
}
__device__ __forceinline__ float dot2u(unsigned int a, unsigned int b, float acc){
  union{unsigned int u; h2 h;} x, y; x.u = a; y.u = b;
#if __has_builtin(__builtin_amdgcn_fdot2)
  return __builtin_amdgcn_fdot2(x.h, y.h, acc, false);
#else
  return acc + (float)x.h.x*(float)y.h.x + (float)x.h.y*(float)y.h.y;
#endif
}
__device__ __forceinline__ float us2f(unsigned short s){
  union{unsigned short s; half_t h;} x; x.s = s; return (float)x.h;
}

// ---- prep: xzc[v][j] = emb_char[v]·char_Wx[:,j] + char_b[j]  (132 x 128) f32
__global__ void k_xzc(const float* __restrict__ emb_char, const float* __restrict__ Wx,
                      const float* __restrict__ bias, float* __restrict__ xzc){
  int v = blockIdx.x, j = threadIdx.x;
  float acc = bias[j];
  #pragma unroll
  for (int k=0;k<DC_;k++) acc += emb_char[v*DC_+k]*Wx[k*(4*UC_)+j];
  xzc[v*(4*UC_)+j] = acc;
}

// ---- prep: chT[j][k] = char_Wh[k][j] as f16  (128 x 32)
__global__ void k_chT(const float* __restrict__ Wh, half_t* __restrict__ o){
  int t = blockIdx.x*256 + threadIdx.x;   // 4096
  int j = t >> 5, k = t & 31;
  o[t] = (half_t)Wh[k*(4*UC_)+j];
}

// ---- prep: whT_h[dir][j][k] = Wh_dir[k][j] as f16  (2 x 256 x 64)
__global__ void k_whT(const float* __restrict__ Whf, const float* __restrict__ Whb,
                      half_t* __restrict__ o){
  int t = blockIdx.x*256 + threadIdx.x;   // 32768
  int dir = t >> 14;
  int j = (t >> 6) & 255;
  int k = t & 63;
  const float* W = dir ? Whb : Whf;
  o[t] = (half_t)W[k*(4*UM_)+j];
}

// ---- prep: wxT_h[dir][jj][k] = Wx_dir[k][jj] f16, k padded 76->96
__global__ void k_wxT(const float* __restrict__ Wxf, const float* __restrict__ Wxb,
                      half_t* __restrict__ o){
  int t = blockIdx.x*256 + threadIdx.x;   // 2*256*96 = 49152
  int dir = t / (256*96);
  int r = t % (256*96);
  int jj = r / 96, k = r % 96;
  const float* W = dir ? Wxb : Wxf;
  o[t] = (k < DIN_) ? (half_t)W[k*(4*UM_)+jj] : (half_t)0.f;
}

// ---- fill x cols [0..16) = word emb, [48..68) = pos, [68..76) = par
__global__ void k_xfill(const int* __restrict__ word_in, const float* __restrict__ emb_wor,
                        const float* __restrict__ pos, const float* __restrict__ par,
                        float* __restrict__ x){
  int r = blockIdx.x*4 + threadIdx.x/80;
  int c = threadIdx.x%80;
  float v;
  if (c < DW_)                     v = emb_wor[word_in[r]*DW_ + c];
  else if (c < DW_+UC_)            return;             // char kernel fills
  else if (c < DW_+UC_+POS_)       v = pos[r*POS_ + (c-(DW_+UC_))];
  else if (c < DIN_)               v = par[r*PAR_ + (c-(DW_+UC_+POS_))];
  else                             return;             // pad, never read
  x[r*XS_ + c] = v;
}

// ---- char LSTM: wave = 1 seq; lane u&31 = unit, lane>>5 = gate-half.
// half0: gates i,f; half1: g,o. 32 packed-f16 weight uints/thread, dot2 math.
// (512,2): 256-reg budget so weights stay in arch VGPRs. Zero barriers in loop.
__global__ __launch_bounds__(512,2) void k_char(const int* __restrict__ char_in,
        const float* __restrict__ xzc, const half_t* __restrict__ chT,
        float* __restrict__ x){
  __shared__ unsigned int hbuf2[8][16];   // h as h2 pairs, per wave
  __shared__ float2 zex[8][64];
  __shared__ int sidx[8*TC_];
  const int tid = threadIdx.x;
  const int w8 = tid >> 6;              // wave = seq slot 0..7
  const int lane = tid & 63;
  const int u = lane & 31;
  const int half = lane >> 5;
  const int seq = blockIdx.x*8 + w8;

  if (tid < 8*TC_) sidx[tid] = char_in[blockIdx.x*(8*TC_) + tid];
  if (half==0 && u<16) hbuf2[w8][u] = 0;

  // cols: a = half*64+u, b = half*64+32+u; chT[col*32+k] -> 16 uints each
  unsigned int wa[16], wb[16];
  {
    const uint4* pa = reinterpret_cast<const uint4*>(chT + (half*64+u)*32);
    const uint4* pb = reinterpret_cast<const uint4*>(chT + (half*64+32+u)*32);
    #pragma unroll
    for (int q=0;q<4;q++){
      uint4 va = pa[q], vb = pb[q];
      wa[q*4+0]=va.x; wa[q*4+1]=va.y; wa[q*4+2]=va.z; wa[q*4+3]=va.w;
      wb[q*4+0]=vb.x; wb[q*4+1]=vb.y; wb[q*4+2]=vb.z; wb[q*4+3]=vb.w;
    }
  }
  __syncthreads();

  float h = 0.f, c = 0.f;
  int idx = sidx[w8*TC_ + 0];
  float za0 = xzc[idx*(4*UC_) + half*64 + u];
  float zb0 = xzc[idx*(4*UC_) + half*64 + 32 + u];

  for (int t=0; t<TC_; t++){
    int idxn = (t+1 < TC_) ? sidx[w8*TC_ + t+1] : 0;
    float zan = xzc[idxn*(4*UC_) + half*64 + u];        // prefetch
    float zbn = xzc[idxn*(4*UC_) + half*64 + 32 + u];

    float za = za0, zb = zb0;
    const uint4* hb = reinterpret_cast<const uint4*>(&hbuf2[w8][0]); // broadcast
    uint4 q0=hb[0], q1=hb[1], q2=hb[2], q3=hb[3];
    unsigned int hu[16] = {q0.x,q0.y,q0.z,q0.w, q1.x,q1.y,q1.z,q1.w,
                           q2.x,q2.y,q2.z,q2.w, q3.x,q3.y,q3.z,q3.w};
    #pragma unroll
    for (int k=0;k<16;k++){
      za = dot2u(wa[k], hu[k], za);
      zb = dot2u(wb[k], hu[k], zb);
    }
    zex[w8][lane] = make_float2(za, zb);  // half1 publishes (zg,zo)
    if (half == 0){
      float2 p = zex[w8][32+u];           // same wave, in-order DS
      float zi = za, zf = zb, zg = p.x, zo = p.y;
      float cn = fast_sig(zf)*c + fast_sig(zi)*fast_tanh(zg);
      float hn = fast_sig(zo)*fast_tanh(cn);
      bool m = (idx != 0);
      c = m ? cn : c;
      h = m ? hn : h;
      reinterpret_cast<half_t*>(&hbuf2[w8][0])[u] = (half_t)h;  // b16 write
    }
    idx = idxn; za0 = zan; zb0 = zbn;
  }
  if (half == 0) x[seq*XS_ + DW_ + u] = h;
}

// ---- xz GEMM via dot2: x staged as packed f16 in LDS (broadcast reads),
// 40 weight uints/thread. Output [row][dir][u*4+g] f16.
__global__ __launch_bounds__(512,2) void k_xz(const float* __restrict__ x,
      const half_t* __restrict__ wxT_h,
      const float* __restrict__ b_f, const float* __restrict__ b_b,
      half_t* __restrict__ xz){
  __shared__ unsigned int xs[16][40];     // 16 rows x 80 halves (76+pad)
  const int j = threadIdx.x;
  const int jj = j & 255;
  const bool bwd = (j >= 256);
  const float bj = bwd ? b_b[jj] : b_f[jj];
  const int u = jj & 63, g = jj >> 6;
  const int ocol = (bwd ? 256 : 0) + u*4 + g;

  unsigned int wq[40];
  {
    const uint4* p = reinterpret_cast<const uint4*>(wxT_h + (size_t)((bwd?256:0)+jj)*96);
    #pragma unroll
    for (int q=0;q<10;q++){
      uint4 v = p[q];
      wq[q*4+0]=v.x; wq[q*4+1]=v.y; wq[q*4+2]=v.z; wq[q*4+3]=v.w;
    }
  }

  const int rowbase = blockIdx.x*16;
  for (int i=j; i<16*40; i+=512){
    int r = i/40, q = i%40;
    unsigned int pk = 0;
    if (q < 38){
      float v0 = x[(size_t)(rowbase+r)*XS_ + 2*q];
      float v1 = x[(size_t)(rowbase+r)*XS_ + 2*q+1];
      union{h2 h; unsigned int u;} cv; cv.h = h2{(half_t)v0,(half_t)v1};
      pk = cv.u;
    }
    xs[r][q] = pk;
  }
  __syncthreads();

  for (int r=0; r<16; r++){
    const uint4* xr = reinterpret_cast<const uint4*>(&xs[r][0]);  // broadcast
    float acc = bj;
    #pragma unroll
    for (int q=0;q<10;q++){
      uint4 v = xr[q];
      acc = dot2u(wq[q*4+0], v.x, acc);
      acc = dot2u(wq[q*4+1], v.y, acc);
      acc = dot2u(wq[q*4+2], v.z, acc);
      acc = dot2u(wq[q*4+3], v.w, acc);
    }
    xz[(size_t)(rowbase+r)*512 + ocol] = (half_t)acc;
  }
}

// ---- word LSTM: ONE WAVE per (batch,dir). Lane u owns unit u, all 4 gates.
// Weights f16 in LDS, XOR-swizzled 16B chunks (uniform bank spread on the
// 64-lane column read). h exchanged via same-wave LDS. ZERO barriers in loop.
__global__ __launch_bounds__(64,1) void k_rnn(const half_t* __restrict__ xz,
      const int* __restrict__ word_in, const half_t* __restrict__ whT_h,
      float* __restrict__ hcat){
  __shared__ uint4 wlds[2048];            // 256 cols x 8 chunks x 16B = 32 KB
  __shared__ uint4 hb4[8];                // h as 64 f16 = 128 B
  __shared__ int wm[T_];
  const int lane = threadIdx.x;
  const int dir = blockIdx.x & 1;
  const int b = blockIdx.x >> 1;

  // stage weights: whT_h[dir][c][k] f16 -> swizzled chunks
  {
    const uint4* src = reinterpret_cast<const uint4*>(whT_h + (size_t)dir*256*64);
    #pragma unroll 4
    for (int i=0;i<32;i++){
      int idx = i*64 + lane;              // chunk id: col = idx>>3, q = idx&7
      int cc = idx >> 3, q = idx & 7;
      wlds[cc*8 + (q ^ (cc & 7))] = src[idx];
    }
  }
  for (int t=lane; t<T_; t+=64) wm[t] = word_in[b*T_ + (dir ? (T_-1-t) : t)];
  if (lane < 8) hb4[lane] = uint4{0,0,0,0};
  __syncthreads();                        // once, after staging

  float h = 0.f, cc_ = 0.f;
  int row0 = b*T_ + (dir ? T_-1 : 0);
  const half_t* xp = xz + (size_t)row0*512 + dir*256 + lane*4;
  const ptrdiff_t dstep = dir ? -512 : 512;
  float* hout = hcat + (size_t)row0*(2*UM_) + dir*UM_ + lane;
  const ptrdiff_t hstep = dir ? -(2*UM_) : (2*UM_);

  ushort4 z0 = *reinterpret_cast<const ushort4*>(xp);
  ushort4 z1 = *reinterpret_cast<const ushort4*>(xp + dstep);

  const int c0 = lane, c1 = 64+lane, c2 = 128+lane, c3 = 192+lane;
  const int x0 = c0&7, x1 = c1&7, x2 = c2&7, x3 = c3&7;

  for (int t=0; t<T_; t++){
    asm volatile("" ::: "memory");        // block LICM of LDS reads
    ushort4 z2 = {0,0,0,0};
    if (t+2 < T_) z2 = *reinterpret_cast<const ushort4*>(xp + 2*dstep); // 2-deep prefetch

    uint4 hc[8];
    #pragma unroll
    for (int q=0;q<8;q++) hc[q] = hb4[q];   // broadcast reads

    float ai0=0.f, ai1=0.f, af0=0.f, af1=0.f;
    float ag0=0.f, ag1=0.f, ao0=0.f, ao1=0.f;
    #pragma unroll
    for (int q=0;q<8;q++){
      uint4 w0 = wlds[c0*8 + (q^x0)];
      uint4 w1 = wlds[c1*8 + (q^x1)];
      uint4 w2 = wlds[c2*8 + (q^x2)];
      uint4 w3 = wlds[c3*8 + (q^x3)];
      ai0 = dot2u(w0.x, hc[q].x, ai0); ai1 = dot2u(w0.y, hc[q].y, ai1);
      ai0 = dot2u(w0.z, hc[q].z, ai0); ai1 = dot2u(w0.w, hc[q].w, ai1);
      af0 = dot2u(w1.x, hc[q].x, af0); af1 = dot2u(w1.y, hc[q].y, af1);
      af0 = dot2u(w1.z, hc[q].z, af0); af1 = dot2u(w1.w, hc[q].w, af1);
      ag0 = dot2u(w2.x, hc[q].x, ag0); ag1 = dot2u(w2.y, hc[q].y, ag1);
      ag0 = dot2u(w2.z, hc[q].z, ag0); ag1 = dot2u(w2.w, hc[q].w, ag1);
      ao0 = dot2u(w3.x, hc[q].x, ao0); ao1 = dot2u(w3.y, hc[q].y, ao1);
      ao0 = dot2u(w3.z, hc[q].z, ao0); ao1 = dot2u(w3.w, hc[q].w, ao1);
    }
    float zi = us2f(z0.x) + (ai0+ai1);
    float zf = us2f(z0.y) + (af0+af1);
    float zg = us2f(z0.z) + (ag0+ag1);
    float zo = us2f(z0.w) + (ao0+ao1);

    int mw = wm[t];                        // uniform broadcast
    float cn = fast_sig(zf)*cc_ + fast_sig(zi)*fast_tanh(zg);
    float hn = fast_sig(zo)*fast_tanh(cn);
    if (mw != 0){ cc_ = cn; h = hn; }
    reinterpret_cast<half_t*>(hb4)[lane] = (half_t)h;  // same-wave, in-order DS
    *hout = h;                             // fire-and-forget
    hout += hstep;
    z0 = z1; z1 = z2; xp += dstep;
  }
}

// ---- dense + softmax
__global__ void k_dense(const float* __restrict__ hcat, const float* __restrict__ W,
                        const float* __restrict__ bias, float* __restrict__ out){
  int r = blockIdx.x*256 + threadIdx.x;
  const float4* h4 = reinterpret_cast<const float4*>(hcat + (size_t)r*(2*UM_));
  float a0=bias[0], a1=bias[1], a2=bias[2], a3=bias[3];
  #pragma unroll
  for (int k4=0;k4<32;k4++){
    float4 hv = h4[k4];
    float he[4] = {hv.x, hv.y, hv.z, hv.w};
    #pragma unroll
    for (int e=0;e<4;e++){
      int k = k4*4+e;
      a0 += he[e]*W[k*4+0]; a1 += he[e]*W[k*4+1];
      a2 += he[e]*W[k*4+2]; a3 += he[e]*W[k*4+3];
    }
  }
  float mx = fmaxf(fmaxf(a0,a1), fmaxf(a2,a3));
  float e0=__expf(a0-mx), e1=__expf(a1-mx), e2=__expf(a2-mx), e3=__expf(a3-mx);
  float s = __builtin_amdgcn_rcpf(e0+e1+e2+e3);
  out[r*4+0]=e0*s; out[r*4+1]=e1*s; out[r*4+2]=e2*s; out[r*4+3]=e3*s;
}

extern "C" void kernel_launch(void* const* d_in, const int* in_sizes, int n_in,
                              void* d_out, int out_size, void* d_ws, size_t ws_size,
                              hipStream_t stream) {
  const int*   word_in  = (const int*)  d_in[0];
  const int*   char_in  = (const int*)  d_in[1];
  const float* inp_pos  = (const float*)d_in[2];
  const float* inp_par  = (const float*)d_in[3];
  const float* emb_wor  = (const float*)d_in[4];
  const float* emb_char = (const float*)d_in[5];
  const float* char_Wx  = (const float*)d_in[6];
  const float* char_Wh  = (const float*)d_in[7];
  const float* char_b   = (const float*)d_in[8];
  const float* fwd_Wx   = (const float*)d_in[9];
  const float* fwd_Wh   = (const float*)d_in[10];
  const float* fwd_b    = (const float*)d_in[11];
  const float* bwd_Wx   = (const float*)d_in[12];
  const float* bwd_Wh   = (const float*)d_in[13];
  const float* bwd_b    = (const float*)d_in[14];
  const float* dense_W  = (const float*)d_in[15];
  const float* dense_b  = (const float*)d_in[16];
  float* out = (float*)d_out;

  float* xw   = (float*)d_ws;                      // NROW*80  f32
  float* hcat = xw + (size_t)NROW*XS_;             // NROW*128 f32
  float* xzc  = hcat + (size_t)NROW*128;           // 132*128  f32
  float* fp   = xzc + (size_t)VC_*128;
  half_t* chT   = (half_t*)fp;                     // 128*32  f16
  half_t* whT_h = chT + 128*32;                    // 2*256*64 f16
  half_t* wxT_h = whT_h + 2*256*64;                // 2*256*96 f16
  half_t* xzw   = wxT_h + 2*256*96;                // NROW*512 f16

  k_xzc  <<<VC_, 4*UC_, 0, stream>>>(emb_char, char_Wx, char_b, xzc);
  k_chT  <<<16, 256, 0, stream>>>(char_Wh, chT);
  k_whT  <<<128, 256, 0, stream>>>(fwd_Wh, bwd_Wh, whT_h);
  k_wxT  <<<192, 256, 0, stream>>>(fwd_Wx, bwd_Wx, wxT_h);
  k_xfill<<<NROW/4, 320, 0, stream>>>(word_in, emb_wor, inp_pos, inp_par, xw);
  k_char <<<NROW/8, 512, 0, stream>>>(char_in, xzc, chT, xw);
  k_xz   <<<NROW/16, 512, 0, stream>>>(xw, wxT_h, fwd_b, bwd_b, xzw);
  k_rnn  <<<2*B_, 64, 0, stream>>>(xzw, word_in, whT_h, hcat);
  k_dense<<<NROW/256, 256, 0, stream>>>(hcat, dense_W, dense_b, out);
}

// Round 10
// 324.476 us; speedup vs baseline: 1.1722x; 1.1722x over previous
//
#include <hip/hip_runtime.h>
#include <hip/hip_bf16.h>

#define B_ 128
#define T_ 300
#define TC_ 20
#define DW_ 16
#define DC_ 32
#define UC_ 32
#define UM_ 64
#define POS_ 20
#define PAR_ 8
#define VW_ 1834
#define VC_ 132
#define DIN_ 76
#define XS_ 80
#define NROW (B_*T_)

typedef _Float16 half_t;
typedef half_t h2 __attribute__((ext_vector_type(2)));

__device__ __forceinline__ float fast_sig(float x){
  return __builtin_amdgcn_rcpf(1.f + __expf(-x));
}
__device__ __forceinline__ float fast_tanh(float x){
  return __builtin_amdgcn_rcpf(1.f + __expf(-2.f*x))*2.f - 1.f;
}
__device__ __forceinline__ float dot2u(unsigned int a, unsigned int b, float acc){
  union{unsigned int u; h2 h;} x, y; x.u = a; y.u = b;
#if __has_builtin(__builtin_amdgcn_fdot2)
  return __builtin_amdgcn_fdot2(x.h, y.h, acc, false);
#else
  return acc + (float)x.h.x*(float)y.h.x + (float)x.h.y*(float)y.h.y;
#endif
}
__device__ __forceinline__ float us2f(unsigned short s){
  union{unsigned short s; half_t h;} x; x.s = s; return (float)x.h;
}

// ---- prep: xzc[v][j] = emb_char[v]·char_Wx[:,j] + char_b[j]  (132 x 128) f32
__global__ void k_xzc(const float* __restrict__ emb_char, const float* __restrict__ Wx,
                      const float* __restrict__ bias, float* __restrict__ xzc){
  int v = blockIdx.x, j = threadIdx.x;
  float acc = bias[j];
  #pragma unroll
  for (int k=0;k<DC_;k++) acc += emb_char[v*DC_+k]*Wx[k*(4*UC_)+j];
  xzc[v*(4*UC_)+j] = acc;
}

// ---- prep: chT[j][k] = char_Wh[k][j] as f16  (128 x 32)
__global__ void k_chT(const float* __restrict__ Wh, half_t* __restrict__ o){
  int t = blockIdx.x*256 + threadIdx.x;   // 4096
  int j = t >> 5, k = t & 31;
  o[t] = (half_t)Wh[k*(4*UC_)+j];
}

// ---- prep: whT_h[dir][j][k] = Wh_dir[k][j] as f16  (2 x 256 x 64)
__global__ void k_whT(const float* __restrict__ Whf, const float* __restrict__ Whb,
                      half_t* __restrict__ o){
  int t = blockIdx.x*256 + threadIdx.x;   // 32768
  int dir = t >> 14;
  int j = (t >> 6) & 255;
  int k = t & 63;
  const float* W = dir ? Whb : Whf;
  o[t] = (half_t)W[k*(4*UM_)+j];
}

// ---- prep: wxT_h[dir][jj][k] = Wx_dir[k][jj] f16, k padded 76->96
__global__ void k_wxT(const float* __restrict__ Wxf, const float* __restrict__ Wxb,
                      half_t* __restrict__ o){
  int t = blockIdx.x*256 + threadIdx.x;   // 2*256*96 = 49152
  int dir = t / (256*96);
  int r = t % (256*96);
  int jj = r / 96, k = r % 96;
  const float* W = dir ? Wxb : Wxf;
  o[t] = (k < DIN_) ? (half_t)W[k*(4*UM_)+jj] : (half_t)0.f;
}

// ---- fill x cols [0..16) = word emb, [48..68) = pos, [68..76) = par
__global__ void k_xfill(const int* __restrict__ word_in, const float* __restrict__ emb_wor,
                        const float* __restrict__ pos, const float* __restrict__ par,
                        float* __restrict__ x){
  int r = blockIdx.x*4 + threadIdx.x/80;
  int c = threadIdx.x%80;
  float v;
  if (c < DW_)                     v = emb_wor[word_in[r]*DW_ + c];
  else if (c < DW_+UC_)            return;             // char kernel fills
  else if (c < DW_+UC_+POS_)       v = pos[r*POS_ + (c-(DW_+UC_))];
  else if (c < DIN_)               v = par[r*PAR_ + (c-(DW_+UC_+POS_))];
  else                             return;             // pad, never read
  x[r*XS_ + c] = v;
}

// ---- char LSTM: wave = 1 seq; lane u&31 = unit, lane>>5 = gate-half.
// half0: gates i,f; half1: g,o. 32 packed-f16 weight uints/thread, dot2 math.
// (512,2): 256-reg budget so weights stay in arch VGPRs. Zero barriers in loop.
__global__ __launch_bounds__(512,2) void k_char(const int* __restrict__ char_in,
        const float* __restrict__ xzc, const half_t* __restrict__ chT,
        float* __restrict__ x){
  __shared__ unsigned int hbuf2[8][16];   // h as h2 pairs, per wave
  __shared__ float2 zex[8][64];
  __shared__ int sidx[8*TC_];
  const int tid = threadIdx.x;
  const int w8 = tid >> 6;              // wave = seq slot 0..7
  const int lane = tid & 63;
  const int u = lane & 31;
  const int half = lane >> 5;
  const int seq = blockIdx.x*8 + w8;

  if (tid < 8*TC_) sidx[tid] = char_in[blockIdx.x*(8*TC_) + tid];
  if (half==0 && u<16) hbuf2[w8][u] = 0;

  // cols: a = half*64+u, b = half*64+32+u; chT[col*32+k] -> 16 uints each
  unsigned int wa[16], wb[16];
  {
    const uint4* pa = reinterpret_cast<const uint4*>(chT + (half*64+u)*32);
    const uint4* pb = reinterpret_cast<const uint4*>(chT + (half*64+32+u)*32);
    #pragma unroll
    for (int q=0;q<4;q++){
      uint4 va = pa[q], vb = pb[q];
      wa[q*4+0]=va.x; wa[q*4+1]=va.y; wa[q*4+2]=va.z; wa[q*4+3]=va.w;
      wb[q*4+0]=vb.x; wb[q*4+1]=vb.y; wb[q*4+2]=vb.z; wb[q*4+3]=vb.w;
    }
  }
  __syncthreads();

  float h = 0.f, c = 0.f;
  int idx = sidx[w8*TC_ + 0];
  float za0 = xzc[idx*(4*UC_) + half*64 + u];
  float zb0 = xzc[idx*(4*UC_) + half*64 + 32 + u];

  for (int t=0; t<TC_; t++){
    int idxn = (t+1 < TC_) ? sidx[w8*TC_ + t+1] : 0;
    float zan = xzc[idxn*(4*UC_) + half*64 + u];        // prefetch
    float zbn = xzc[idxn*(4*UC_) + half*64 + 32 + u];

    float za = za0, zb = zb0;
    const uint4* hb = reinterpret_cast<const uint4*>(&hbuf2[w8][0]); // broadcast
    uint4 q0=hb[0], q1=hb[1], q2=hb[2], q3=hb[3];
    unsigned int hu[16] = {q0.x,q0.y,q0.z,q0.w, q1.x,q1.y,q1.z,q1.w,
                           q2.x,q2.y,q2.z,q2.w, q3.x,q3.y,q3.z,q3.w};
    #pragma unroll
    for (int k=0;k<16;k++){
      za = dot2u(wa[k], hu[k], za);
      zb = dot2u(wb[k], hu[k], zb);
    }
    zex[w8][lane] = make_float2(za, zb);  // half1 publishes (zg,zo)
    if (half == 0){
      float2 p = zex[w8][32+u];           // same wave, in-order DS
      float zi = za, zf = zb, zg = p.x, zo = p.y;
      float cn = fast_sig(zf)*c + fast_sig(zi)*fast_tanh(zg);
      float hn = fast_sig(zo)*fast_tanh(cn);
      bool m = (idx != 0);
      c = m ? cn : c;
      h = m ? hn : h;
      reinterpret_cast<half_t*>(&hbuf2[w8][0])[u] = (half_t)h;  // b16 write
    }
    idx = idxn; za0 = zan; zb0 = zbn;
  }
  if (half == 0) x[seq*XS_ + DW_ + u] = h;
}

// ---- xz GEMM via dot2: x staged as packed f16 in LDS (broadcast reads),
// 40 weight uints/thread. Output [row][(dir*4+g)*64+u] f16.
__global__ __launch_bounds__(512,2) void k_xz(const float* __restrict__ x,
      const half_t* __restrict__ wxT_h,
      const float* __restrict__ b_f, const float* __restrict__ b_b,
      half_t* __restrict__ xz){
  __shared__ unsigned int xs[16][40];     // 16 rows x 80 halves (76+pad)
  const int j = threadIdx.x;
  const int jj = j & 255;
  const bool bwd = (j >= 256);
  const float bj = bwd ? b_b[jj] : b_f[jj];
  const int u = jj & 63, g = jj >> 6;
  const int ocol = ((bwd ? 4 : 0) + g)*64 + u;

  unsigned int wq[40];
  {
    const uint4* p = reinterpret_cast<const uint4*>(wxT_h + (size_t)((bwd?256:0)+jj)*96);
    #pragma unroll
    for (int q=0;q<10;q++){
      uint4 v = p[q];
      wq[q*4+0]=v.x; wq[q*4+1]=v.y; wq[q*4+2]=v.z; wq[q*4+3]=v.w;
    }
  }

  const int rowbase = blockIdx.x*16;
  for (int i=j; i<16*40; i+=512){
    int r = i/40, q = i%40;
    unsigned int pk = 0;
    if (q < 38){
      float v0 = x[(size_t)(rowbase+r)*XS_ + 2*q];
      float v1 = x[(size_t)(rowbase+r)*XS_ + 2*q+1];
      union{h2 h; unsigned int u;} cv; cv.h = h2{(half_t)v0,(half_t)v1};
      pk = cv.u;
    }
    xs[r][q] = pk;
  }
  __syncthreads();

  for (int r=0; r<16; r++){
    const uint4* xr = reinterpret_cast<const uint4*>(&xs[r][0]);  // broadcast
    float acc = bj;
    #pragma unroll
    for (int q=0;q<10;q++){
      uint4 v = xr[q];
      acc = dot2u(wq[q*4+0], v.x, acc);
      acc = dot2u(wq[q*4+1], v.y, acc);
      acc = dot2u(wq[q*4+2], v.z, acc);
      acc = dot2u(wq[q*4+3], v.w, acc);
    }
    xz[(size_t)(rowbase+r)*512 + ocol] = (half_t)acc;
  }
}

// ---- word LSTM: block = (batch,dir), 4 waves, GATE-SPLIT.
// Wave w = gate w, lane l = unit l: full 64-k dot product (32 dot2).
// Cross-wave exchange = ONE post-nonlin f32 per (gate,unit): write 1 b32,
// barrier, read 4 b32, 5-op combine. h per-wave redundant (no 2nd barrier).
__global__ __launch_bounds__(256,1) void k_rnn(const half_t* __restrict__ xz,
      const int* __restrict__ word_in, const half_t* __restrict__ whT_h,
      float* __restrict__ hcat){
  __shared__ float gbuf[2][4][64];        // [buf][gate][unit] post-nonlin
  __shared__ unsigned int hbuf2[4][32];   // per-wave h copy (64 f16)
  __shared__ int wm[T_];
  const int j = threadIdx.x;
  const int w = j >> 6;                   // gate 0=i 1=f 2=g 3=o
  const int l = j & 63;                   // unit
  const int dir = blockIdx.x & 1;
  const int b = blockIdx.x >> 1;

  // weights: col = w*64+l, k=0..63 f16 -> 32 uints
  unsigned int wt[32];
  {
    const uint4* p = reinterpret_cast<const uint4*>(whT_h + ((size_t)dir*256 + w*64 + l)*64);
    #pragma unroll
    for (int q=0;q<8;q++){
      uint4 v = p[q];
      wt[q*4+0]=v.x; wt[q*4+1]=v.y; wt[q*4+2]=v.z; wt[q*4+3]=v.w;
    }
  }
  for (int t=j; t<T_; t+=256) wm[t] = word_in[b*T_ + (dir ? (T_-1-t) : t)];
  if (l < 32) hbuf2[w][l] = 0;
  __syncthreads();

  float h = 0.f, c_ = 0.f;
  int row0 = b*T_ + (dir ? T_-1 : 0);
  const half_t* xp = xz + (size_t)row0*512 + (dir*4+w)*64 + l;
  const ptrdiff_t dstep = dir ? -512 : 512;
  float* hout = hcat + (size_t)row0*(2*UM_) + dir*UM_ + l;
  const ptrdiff_t hstep = dir ? -(2*UM_) : (2*UM_);

  unsigned short zx0 = *reinterpret_cast<const unsigned short*>(xp);
  unsigned short zx1 = *reinterpret_cast<const unsigned short*>(xp + dstep);

  for (int t=0; t<T_; t++){
    unsigned short zx2 = 0;
    if (t+2 < T_) zx2 = *reinterpret_cast<const unsigned short*>(xp + 2*dstep);

    const uint4* hb = reinterpret_cast<const uint4*>(&hbuf2[w][0]);  // broadcast
    float a0=0.f, a1=0.f;
    #pragma unroll
    for (int q=0;q<8;q++){
      uint4 hv = hb[q];
      a0 = dot2u(wt[q*4+0], hv.x, a0);
      a1 = dot2u(wt[q*4+1], hv.y, a1);
      a0 = dot2u(wt[q*4+2], hv.z, a0);
      a1 = dot2u(wt[q*4+3], hv.w, a1);
    }
    float z = us2f(zx0) + (a0+a1);
    float nl = (w == 2) ? fast_tanh(z) : fast_sig(z);   // own gate nonlin
    gbuf[t&1][w][l] = nl;
    asm volatile("s_waitcnt lgkmcnt(0)" ::: "memory");
    __builtin_amdgcn_s_barrier();
    asm volatile("" ::: "memory");

    float si = gbuf[t&1][0][l];
    float sf = gbuf[t&1][1][l];
    float tg = gbuf[t&1][2][l];
    float so = gbuf[t&1][3][l];
    int mw = wm[t];
    float cn = sf*c_ + si*tg;
    float hn = so*fast_tanh(cn);
    if (mw != 0){ c_ = cn; h = hn; }      // bit-identical across waves
    reinterpret_cast<half_t*>(&hbuf2[w][0])[l] = (half_t)h;  // own-wave copy
    if (w == 0) *hout = h;                // fire-and-forget
    hout += hstep;
    zx0 = zx1; zx1 = zx2; xp += dstep;
  }
}

// ---- dense + softmax
__global__ void k_dense(const float* __restrict__ hcat, const float* __restrict__ W,
                        const float* __restrict__ bias, float* __restrict__ out){
  int r = blockIdx.x*256 + threadIdx.x;
  const float4* h4 = reinterpret_cast<const float4*>(hcat + (size_t)r*(2*UM_));
  float a0=bias[0], a1=bias[1], a2=bias[2], a3=bias[3];
  #pragma unroll
  for (int k4=0;k4<32;k4++){
    float4 hv = h4[k4];
    float he[4] = {hv.x, hv.y, hv.z, hv.w};
    #pragma unroll
    for (int e=0;e<4;e++){
      int k = k4*4+e;
      a0 += he[e]*W[k*4+0]; a1 += he[e]*W[k*4+1];
      a2 += he[e]*W[k*4+2]; a3 += he[e]*W[k*4+3];
    }
  }
  float mx = fmaxf(fmaxf(a0,a1), fmaxf(a2,a3));
  float e0=__expf(a0-mx), e1=__expf(a1-mx), e2=__expf(a2-mx), e3=__expf(a3-mx);
  float s = __builtin_amdgcn_rcpf(e0+e1+e2+e3);
  out[r*4+0]=e0*s; out[r*4+1]=e1*s; out[r*4+2]=e2*s; out[r*4+3]=e3*s;
}

extern "C" void kernel_launch(void* const* d_in, const int* in_sizes, int n_in,
                              void* d_out, int out_size, void* d_ws, size_t ws_size,
                              hipStream_t stream) {
  const int*   word_in  = (const int*)  d_in[0];
  const int*   char_in  = (const int*)  d_in[1];
  const float* inp_pos  = (const float*)d_in[2];
  const float* inp_par  = (const float*)d_in[3];
  const float* emb_wor  = (const float*)d_in[4];
  const float* emb_char = (const float*)d_in[5];
  const float* char_Wx  = (const float*)d_in[6];
  const float* char_Wh  = (const float*)d_in[7];
  const float* char_b   = (const float*)d_in[8];
  const float* fwd_Wx   = (const float*)d_in[9];
  const float* fwd_Wh   = (const float*)d_in[10];
  const float* fwd_b    = (const float*)d_in[11];
  const float* bwd_Wx   = (const float*)d_in[12];
  const float* bwd_Wh   = (const float*)d_in[13];
  const float* bwd_b    = (const float*)d_in[14];
  const float* dense_W  = (const float*)d_in[15];
  const float* dense_b  = (const float*)d_in[16];
  float* out = (float*)d_out;

  float* xw   = (float*)d_ws;                      // NROW*80  f32
  float* hcat = xw + (size_t)NROW*XS_;             // NROW*128 f32
  float* xzc  = hcat + (size_t)NROW*128;           // 132*128  f32
  float* fp   = xzc + (size_t)VC_*128;
  half_t* chT   = (half_t*)fp;                     // 128*32  f16
  half_t* whT_h = chT + 128*32;                    // 2*256*64 f16
  half_t* wxT_h = whT_h + 2*256*64;                // 2*256*96 f16
  half_t* xzw   = wxT_h + 2*256*96;                // NROW*512 f16

  k_xzc  <<<VC_, 4*UC_, 0, stream>>>(emb_char, char_Wx, char_b, xzc);
  k_chT  <<<16, 256, 0, stream>>>(char_Wh, chT);
  k_whT  <<<128, 256, 0, stream>>>(fwd_Wh, bwd_Wh, whT_h);
  k_wxT  <<<192, 256, 0, stream>>>(fwd_Wx, bwd_Wx, wxT_h);
  k_xfill<<<NROW/4, 320, 0, stream>>>(word_in, emb_wor, inp_pos, inp_par, xw);
  k_char <<<NROW/8, 512, 0, stream>>>(char_in, xzc, chT, xw);
  k_xz   <<<NROW/16, 512, 0, stream>>>(xw, wxT_h, fwd_b, bwd_b, xzw);
  k_rnn  <<<2*B_, 256, 0, stream>>>(xzw, word_in, whT_h, hcat);
  k_dense<<<NROW/256, 256, 0, stream>>>(hcat, dense_W, dense_b, out);
}

// Round 11
// 316.068 us; speedup vs baseline: 1.2034x; 1.0266x over previous
//
#include <hip/hip_runtime.h>
#include <hip/hip_bf16.h>

#define B_ 128
#define T_ 300
#define TC_ 20
#define DW_ 16
#define DC_ 32
#define UC_ 32
#define UM_ 64
#define POS_ 20
#define PAR_ 8
#define VW_ 1834
#define VC_ 132
#define DIN_ 76
#define XS_ 80
#define NROW (B_*T_)

typedef _Float16 half_t;
typedef half_t h2 __attribute__((ext_vector_type(2)));

__device__ __forceinline__ float fast_sig(float x){
  return __builtin_amdgcn_rcpf(1.f + __expf(-x));
}
__device__ __forceinline__ float fast_tanh(float x){
  return __builtin_amdgcn_rcpf(1.f + __expf(-2.f*x))*2.f - 1.f;
}
__device__ __forceinline__ float dot2u(unsigned int a, unsigned int b, float acc){
  union{unsigned int u; h2 h;} x, y; x.u = a; y.u = b;
#if __has_builtin(__builtin_amdgcn_fdot2)
  return __builtin_amdgcn_fdot2(x.h, y.h, acc, false);
#else
  return acc + (float)x.h.x*(float)y.h.x + (float)x.h.y*(float)y.h.y;
#endif
}
__device__ __forceinline__ float us2f(unsigned short s){
  union{unsigned short s; half_t h;} x; x.s = s; return (float)x.h;
}

// ---- prep: xzc[v][j] = emb_char[v]·char_Wx[:,j] + char_b[j]  (132 x 128) f32
__global__ void k_xzc(const float* __restrict__ emb_char, const float* __restrict__ Wx,
                      const float* __restrict__ bias, float* __restrict__ xzc){
  int v = blockIdx.x, j = threadIdx.x;
  float acc = bias[j];
  #pragma unroll
  for (int k=0;k<DC_;k++) acc += emb_char[v*DC_+k]*Wx[k*(4*UC_)+j];
  xzc[v*(4*UC_)+j] = acc;
}

// ---- prep: chT[j][k] = char_Wh[k][j] as f16  (128 x 32)
__global__ void k_chT(const float* __restrict__ Wh, half_t* __restrict__ o){
  int t = blockIdx.x*256 + threadIdx.x;   // 4096
  int j = t >> 5, k = t & 31;
  o[t] = (half_t)Wh[k*(4*UC_)+j];
}

// ---- prep: whT_h[dir][j][k] = Wh_dir[k][j] as f16  (2 x 256 x 64)
__global__ void k_whT(const float* __restrict__ Whf, const float* __restrict__ Whb,
                      half_t* __restrict__ o){
  int t = blockIdx.x*256 + threadIdx.x;   // 32768
  int dir = t >> 14;
  int j = (t >> 6) & 255;
  int k = t & 63;
  const float* W = dir ? Whb : Whf;
  o[t] = (half_t)W[k*(4*UM_)+j];
}

// ---- prep: wxT_h[dir][jj][k] = Wx_dir[k][jj] f16, k padded 76->96
__global__ void k_wxT(const float* __restrict__ Wxf, const float* __restrict__ Wxb,
                      half_t* __restrict__ o){
  int t = blockIdx.x*256 + threadIdx.x;   // 2*256*96 = 49152
  int dir = t / (256*96);
  int r = t % (256*96);
  int jj = r / 96, k = r % 96;
  const float* W = dir ? Wxb : Wxf;
  o[t] = (k < DIN_) ? (half_t)W[k*(4*UM_)+jj] : (half_t)0.f;
}

// ---- fill x cols [0..16) = word emb, [48..68) = pos, [68..76) = par
__global__ void k_xfill(const int* __restrict__ word_in, const float* __restrict__ emb_wor,
                        const float* __restrict__ pos, const float* __restrict__ par,
                        float* __restrict__ x){
  int r = blockIdx.x*4 + threadIdx.x/80;
  int c = threadIdx.x%80;
  float v;
  if (c < DW_)                     v = emb_wor[word_in[r]*DW_ + c];
  else if (c < DW_+UC_)            return;             // char kernel fills
  else if (c < DW_+UC_+POS_)       v = pos[r*POS_ + (c-(DW_+UC_))];
  else if (c < DIN_)               v = par[r*PAR_ + (c-(DW_+UC_+POS_))];
  else                             return;             // pad, never read
  x[r*XS_ + c] = v;
}

// ---- char LSTM: wave = 1 seq; lane u&31 = unit, lane>>5 = gate-half.
// half0: gates i,f; half1: g,o. 32 packed-f16 weight uints/thread, dot2 math.
// (512,2): 256-reg budget so weights stay in arch VGPRs. Zero barriers in loop.
__global__ __launch_bounds__(512,2) void k_char(const int* __restrict__ char_in,
        const float* __restrict__ xzc, const half_t* __restrict__ chT,
        float* __restrict__ x){
  __shared__ unsigned int hbuf2[8][16];   // h as h2 pairs, per wave
  __shared__ float2 zex[8][64];
  __shared__ int sidx[8*TC_];
  const int tid = threadIdx.x;
  const int w8 = tid >> 6;              // wave = seq slot 0..7
  const int lane = tid & 63;
  const int u = lane & 31;
  const int half = lane >> 5;
  const int seq = blockIdx.x*8 + w8;

  if (tid < 8*TC_) sidx[tid] = char_in[blockIdx.x*(8*TC_) + tid];
  if (half==0 && u<16) hbuf2[w8][u] = 0;

  // cols: a = half*64+u, b = half*64+32+u; chT[col*32+k] -> 16 uints each
  unsigned int wa[16], wb[16];
  {
    const uint4* pa = reinterpret_cast<const uint4*>(chT + (half*64+u)*32);
    const uint4* pb = reinterpret_cast<const uint4*>(chT + (half*64+32+u)*32);
    #pragma unroll
    for (int q=0;q<4;q++){
      uint4 va = pa[q], vb = pb[q];
      wa[q*4+0]=va.x; wa[q*4+1]=va.y; wa[q*4+2]=va.z; wa[q*4+3]=va.w;
      wb[q*4+0]=vb.x; wb[q*4+1]=vb.y; wb[q*4+2]=vb.z; wb[q*4+3]=vb.w;
    }
  }
  __syncthreads();

  float h = 0.f, c = 0.f;
  int idx = sidx[w8*TC_ + 0];
  float za0 = xzc[idx*(4*UC_) + half*64 + u];
  float zb0 = xzc[idx*(4*UC_) + half*64 + 32 + u];

  for (int t=0; t<TC_; t++){
    int idxn = (t+1 < TC_) ? sidx[w8*TC_ + t+1] : 0;
    float zan = xzc[idxn*(4*UC_) + half*64 + u];        // prefetch
    float zbn = xzc[idxn*(4*UC_) + half*64 + 32 + u];

    float za = za0, zb = zb0;
    const uint4* hb = reinterpret_cast<const uint4*>(&hbuf2[w8][0]); // broadcast
    uint4 q0=hb[0], q1=hb[1], q2=hb[2], q3=hb[3];
    unsigned int hu[16] = {q0.x,q0.y,q0.z,q0.w, q1.x,q1.y,q1.z,q1.w,
                           q2.x,q2.y,q2.z,q2.w, q3.x,q3.y,q3.z,q3.w};
    #pragma unroll
    for (int k=0;k<16;k++){
      za = dot2u(wa[k], hu[k], za);
      zb = dot2u(wb[k], hu[k], zb);
    }
    zex[w8][lane] = make_float2(za, zb);  // half1 publishes (zg,zo)
    if (half == 0){
      float2 p = zex[w8][32+u];           // same wave, in-order DS
      float zi = za, zf = zb, zg = p.x, zo = p.y;
      float cn = fast_sig(zf)*c + fast_sig(zi)*fast_tanh(zg);
      float hn = fast_sig(zo)*fast_tanh(cn);
      bool m = (idx != 0);
      c = m ? cn : c;
      h = m ? hn : h;
      reinterpret_cast<half_t*>(&hbuf2[w8][0])[u] = (half_t)h;  // b16 write
    }
    idx = idxn; za0 = zan; zb0 = zbn;
  }
  if (half == 0) x[seq*XS_ + DW_ + u] = h;
}

// ---- xz GEMM via dot2: x staged as packed f16 in LDS (broadcast reads),
// 40 weight uints/thread. Output [row][dir*256 + u*4 + g] f16.
__global__ __launch_bounds__(512,2) void k_xz(const float* __restrict__ x,
      const half_t* __restrict__ wxT_h,
      const float* __restrict__ b_f, const float* __restrict__ b_b,
      half_t* __restrict__ xz){
  __shared__ unsigned int xs[16][40];     // 16 rows x 80 halves (76+pad)
  const int j = threadIdx.x;
  const int jj = j & 255;
  const bool bwd = (j >= 256);
  const float bj = bwd ? b_b[jj] : b_f[jj];
  const int u = jj & 63, g = jj >> 6;
  const int ocol = (bwd ? 256 : 0) + u*4 + g;

  unsigned int wq[40];
  {
    const uint4* p = reinterpret_cast<const uint4*>(wxT_h + (size_t)((bwd?256:0)+jj)*96);
    #pragma unroll
    for (int q=0;q<10;q++){
      uint4 v = p[q];
      wq[q*4+0]=v.x; wq[q*4+1]=v.y; wq[q*4+2]=v.z; wq[q*4+3]=v.w;
    }
  }

  const int rowbase = blockIdx.x*16;
  for (int i=j; i<16*40; i+=512){
    int r = i/40, q = i%40;
    unsigned int pk = 0;
    if (q < 38){
      float v0 = x[(size_t)(rowbase+r)*XS_ + 2*q];
      float v1 = x[(size_t)(rowbase+r)*XS_ + 2*q+1];
      union{h2 h; unsigned int u;} cv; cv.h = h2{(half_t)v0,(half_t)v1};
      pk = cv.u;
    }
    xs[r][q] = pk;
  }
  __syncthreads();

  for (int r=0; r<16; r++){
    const uint4* xr = reinterpret_cast<const uint4*>(&xs[r][0]);  // broadcast
    float acc = bj;
    #pragma unroll
    for (int q=0;q<10;q++){
      uint4 v = xr[q];
      acc = dot2u(wq[q*4+0], v.x, acc);
      acc = dot2u(wq[q*4+1], v.y, acc);
      acc = dot2u(wq[q*4+2], v.z, acc);
      acc = dot2u(wq[q*4+3], v.w, acc);
    }
    xz[(size_t)(rowbase+r)*512 + ocol] = (half_t)acc;
  }
}

// ---- word LSTM: ONE WAVE per (batch,dir). Lane l owns unit l, ALL 4 gates
// (full 64-k dot2 per gate, 128 dot2/lane, 128 weight uints UNPINNED).
// h exchange: 1 ds_write_b16 + 8 broadcast ds_read_b128, same-wave in-order.
// ZERO barriers, zero cross-wave traffic.
__global__ __launch_bounds__(64,1) void k_rnn(const half_t* __restrict__ xz,
      const int* __restrict__ word_in, const half_t* __restrict__ whT_h,
      float* __restrict__ hcat){
  __shared__ half_t hbuf[64];
  __shared__ int wm[T_];
  const int l = threadIdx.x;
  const int dir = blockIdx.x & 1;
  const int b = blockIdx.x >> 1;

  // weights: column (gate g, unit l) -> 32 uints each, 128 total
  unsigned int wt[4][32];
  #pragma unroll
  for (int g=0; g<4; g++){
    const uint4* p = reinterpret_cast<const uint4*>(whT_h + ((size_t)dir*256 + g*64 + l)*64);
    #pragma unroll
    for (int q=0;q<8;q++){
      uint4 v = p[q];
      wt[g][q*4+0]=v.x; wt[g][q*4+1]=v.y; wt[g][q*4+2]=v.z; wt[g][q*4+3]=v.w;
    }
  }
  for (int t=l; t<T_; t+=64) wm[t] = word_in[b*T_ + (dir ? (T_-1-t) : t)];
  hbuf[l] = (half_t)0.f;

  float h = 0.f, c_ = 0.f;
  int row0 = b*T_ + (dir ? T_-1 : 0);
  const half_t* xp = xz + (size_t)row0*512 + dir*256 + l*4;
  const ptrdiff_t dstep = dir ? -512 : 512;
  float* hout = hcat + (size_t)row0*(2*UM_) + dir*UM_ + l;
  const ptrdiff_t hstep = dir ? -(2*UM_) : (2*UM_);

  ushort4 z0 = *reinterpret_cast<const ushort4*>(xp);
  ushort4 z1 = *reinterpret_cast<const ushort4*>(xp + dstep);

  for (int t=0; t<T_; t++){
    ushort4 z2 = {0,0,0,0};
    if (t+2 < T_) z2 = *reinterpret_cast<const ushort4*>(xp + 2*dstep); // prefetch

    // full h: 64 f16 = 8 x b128 broadcast reads
    const uint4* hb = reinterpret_cast<const uint4*>(hbuf);
    float ai0=0.f, ai1=0.f, af0=0.f, af1=0.f;
    float ag0=0.f, ag1=0.f, ao0=0.f, ao1=0.f;
    #pragma unroll
    for (int q=0;q<8;q++){
      uint4 hv = hb[q];
      ai0 = dot2u(wt[0][q*4+0], hv.x, ai0); ai1 = dot2u(wt[0][q*4+1], hv.y, ai1);
      ai0 = dot2u(wt[0][q*4+2], hv.z, ai0); ai1 = dot2u(wt[0][q*4+3], hv.w, ai1);
      af0 = dot2u(wt[1][q*4+0], hv.x, af0); af1 = dot2u(wt[1][q*4+1], hv.y, af1);
      af0 = dot2u(wt[1][q*4+2], hv.z, af0); af1 = dot2u(wt[1][q*4+3], hv.w, af1);
      ag0 = dot2u(wt[2][q*4+0], hv.x, ag0); ag1 = dot2u(wt[2][q*4+1], hv.y, ag1);
      ag0 = dot2u(wt[2][q*4+2], hv.z, ag0); ag1 = dot2u(wt[2][q*4+3], hv.w, ag1);
      ao0 = dot2u(wt[3][q*4+0], hv.x, ao0); ao1 = dot2u(wt[3][q*4+1], hv.y, ao1);
      ao0 = dot2u(wt[3][q*4+2], hv.z, ao0); ao1 = dot2u(wt[3][q*4+3], hv.w, ao1);
    }
    float zi = us2f(z0.x) + (ai0+ai1);
    float zf = us2f(z0.y) + (af0+af1);
    float zg = us2f(z0.z) + (ag0+ag1);
    float zo = us2f(z0.w) + (ao0+ao1);

    int mw = wm[t];                        // uniform LDS read
    float cn = fast_sig(zf)*c_ + fast_sig(zi)*fast_tanh(zg);
    float hn = fast_sig(zo)*fast_tanh(cn);
    if (mw != 0){ c_ = cn; h = hn; }
    hbuf[l] = (half_t)h;                   // same-wave, in-order DS pipe
    *hout = h;                             // fire-and-forget coalesced store
    hout += hstep;
    z0 = z1; z1 = z2; xp += dstep;
  }
}

// ---- dense + softmax
__global__ void k_dense(const float* __restrict__ hcat, const float* __restrict__ W,
                        const float* __restrict__ bias, float* __restrict__ out){
  int r = blockIdx.x*256 + threadIdx.x;
  const float4* h4 = reinterpret_cast<const float4*>(hcat + (size_t)r*(2*UM_));
  float a0=bias[0], a1=bias[1], a2=bias[2], a3=bias[3];
  #pragma unroll
  for (int k4=0;k4<32;k4++){
    float4 hv = h4[k4];
    float he[4] = {hv.x, hv.y, hv.z, hv.w};
    #pragma unroll
    for (int e=0;e<4;e++){
      int k = k4*4+e;
      a0 += he[e]*W[k*4+0]; a1 += he[e]*W[k*4+1];
      a2 += he[e]*W[k*4+2]; a3 += he[e]*W[k*4+3];
    }
  }
  float mx = fmaxf(fmaxf(a0,a1), fmaxf(a2,a3));
  float e0=__expf(a0-mx), e1=__expf(a1-mx), e2=__expf(a2-mx), e3=__expf(a3-mx);
  float s = __builtin_amdgcn_rcpf(e0+e1+e2+e3);
  out[r*4+0]=e0*s; out[r*4+1]=e1*s; out[r*4+2]=e2*s; out[r*4+3]=e3*s;
}

extern "C" void kernel_launch(void* const* d_in, const int* in_sizes, int n_in,
                              void* d_out, int out_size, void* d_ws, size_t ws_size,
                              hipStream_t stream) {
  const int*   word_in  = (const int*)  d_in[0];
  const int*   char_in  = (const int*)  d_in[1];
  const float* inp_pos  = (const float*)d_in[2];
  const float* inp_par  = (const float*)d_in[3];
  const float* emb_wor  = (const float*)d_in[4];
  const float* emb_char = (const float*)d_in[5];
  const float* char_Wx  = (const float*)d_in[6];
  const float* char_Wh  = (const float*)d_in[7];
  const float* char_b   = (const float*)d_in[8];
  const float* fwd_Wx   = (const float*)d_in[9];
  const float* fwd_Wh   = (const float*)d_in[10];
  const float* fwd_b    = (const float*)d_in[11];
  const float* bwd_Wx   = (const float*)d_in[12];
  const float* bwd_Wh   = (const float*)d_in[13];
  const float* bwd_b    = (const float*)d_in[14];
  const float* dense_W  = (const float*)d_in[15];
  const float* dense_b  = (const float*)d_in[16];
  float* out = (float*)d_out;

  float* xw   = (float*)d_ws;                      // NROW*80  f32
  float* hcat = xw + (size_t)NROW*XS_;             // NROW*128 f32
  float* xzc  = hcat + (size_t)NROW*128;           // 132*128  f32
  float* fp   = xzc + (size_t)VC_*128;
  half_t* chT   = (half_t*)fp;                     // 128*32  f16
  half_t* whT_h = chT + 128*32;                    // 2*256*64 f16
  half_t* wxT_h = whT_h + 2*256*64;                // 2*256*96 f16
  half_t* xzw   = wxT_h + 2*256*96;                // NROW*512 f16

  k_xzc  <<<VC_, 4*UC_, 0, stream>>>(emb_char, char_Wx, char_b, xzc);
  k_chT  <<<16, 256, 0, stream>>>(char_Wh, chT);
  k_whT  <<<128, 256, 0, stream>>>(fwd_Wh, bwd_Wh, whT_h);
  k_wxT  <<<192, 256, 0, stream>>>(fwd_Wx, bwd_Wx, wxT_h);
  k_xfill<<<NROW/4, 320, 0, stream>>>(word_in, emb_wor, inp_pos, inp_par, xw);
  k_char <<<NROW/8, 512, 0, stream>>>(char_in, xzc, chT, xw);
  k_xz   <<<NROW/16, 512, 0, stream>>>(xw, wxT_h, fwd_b, bwd_b, xzw);
  k_rnn  <<<2*B_, 64, 0, stream>>>(xzw, word_in, whT_h, hcat);
  k_dense<<<NROW/256, 256, 0, stream>>>(hcat, dense_W, dense_b, out);
}